// Round 11
// baseline (461.529 us; speedup 1.0000x reference)
//
#include <hip/hip_runtime.h>
#include <hip/hip_bf16.h>
#include <math.h>

#define MBLK    64
#define H0_OFF  65536                 // act: 64 rows x 1024B (512 bf16), XOR-swizzled (row&15)<<4
#define LDSB    (H0_OFF + 64*64)      // +h0: 64 rows x 64B -> 69632 (2 blocks/CU)

// packed bf16 weight offsets (ushort elements) inside d_ws
// layout per layer: [nb(8)][ks(NC2)][nr(2)][lane(64)][j(8)]  (coalesced per-wave loads)
// n = nb*64 + nr*32 + (lane&31); k = ks*16 + (lane>>5)*8 + j
#define OFF_W1  0
#define OFF_W2  16384                    // 8*2*2*512
#define OFF_WS1 (16384+262144)           // 278528
#define OFF_WS2 (278528+278528)          // 557056
#define OFF_WO  (557056+262144)          // 819200 (wo row-major, 1024)
#define NPACK   (819200+1024)            // 820224

typedef __attribute__((ext_vector_type(8)))  short bf16x8;
typedef __attribute__((ext_vector_type(16))) float f32x16;

struct ResArr { int r[10]; };

__device__ __forceinline__ unsigned short f2bf(float f) {
    unsigned u = __float_as_uint(f);
    u += 0x7FFFu + ((u >> 16) & 1u);       // RNE — matches numpy; do NOT use v_cvt_pk_bf16_f32
    return (unsigned short)(u >> 16);
}
__device__ __forceinline__ float bf2f(unsigned short h) {
    return __uint_as_float(((unsigned)h) << 16);
}

__global__ void pack_weights(const float* __restrict__ w1, const float* __restrict__ w2,
                             const float* __restrict__ ws1, const float* __restrict__ ws2,
                             const float* __restrict__ wo, unsigned short* __restrict__ out)
{
    int i = blockIdx.x * 256 + threadIdx.x;
    if (i >= NPACK) return;
    float v;
    if (i < OFF_WO) {
        int il, NC2, K_src, K_valid;
        const float* src;
        if (i < OFF_W2)       { il = i;           NC2 = 2;  K_src = 22;  K_valid = 22;  src = w1;  }
        else if (i < OFF_WS1) { il = i - OFF_W2;  NC2 = 32; K_src = 512; K_valid = 512; src = w2;  }
        else if (i < OFF_WS2) { il = i - OFF_WS1; NC2 = 34; K_src = 534; K_valid = 534; src = ws1; }
        else                  { il = i - OFF_WS2; NC2 = 32; K_src = 512; K_valid = 512; src = ws2; }
        int blk  = il >> 9, idx = il & 511;
        int lane = idx >> 3, j = idx & 7;
        int nr   = blk & 1;
        int rest = blk >> 1;
        int c    = rest % NC2;
        int nb   = rest / NC2;
        int n = nb * 64 + nr * 32 + (lane & 31);
        int k = c * 16 + (lane >> 5) * 8 + j;
        v = (k < K_valid) ? src[n * K_src + k] : 0.f;
    } else {
        v = wo[i - OFF_WO];
    }
    out[i] = f2bf(v);
}

// One MLP layer, in-place on the 64x512 act buffer. 8 waves; wave owns 64 rows x 64 cols
// as 2x2 tiles of 32x32x16 MFMA. Swapped operands: acc = mfma(W, act).
// C layout (m74/m101): col(lane&31)=act row, row=(reg&3)+8*(reg>>2)+4*(lane>>5) = n-local
template<int KSTEPS, bool TAIL, bool PREBAR>
__device__ __forceinline__ void mlp_layer(char* sm, const unsigned short* __restrict__ Wl,
                                          const float* __restrict__ bias,
                                          int wid, int lane)
{
    constexpr int NC2 = KSTEPS + (TAIL ? 2 : 0);
    const int n0  = wid * 64;
    const int l31 = lane & 31;
    const int hi  = lane >> 5;              // k-half 0/1

    const unsigned short* wnb = Wl + (unsigned)(wid * NC2) * 1024 + (lane << 3);

    f32x16 acc[2][2];
    #pragma unroll
    for (int mr = 0; mr < 2; ++mr)
        #pragma unroll
        for (int nr = 0; nr < 2; ++nr)
            #pragma unroll
            for (int e = 0; e < 16; ++e) acc[mr][nr][e] = 0.f;

    #pragma unroll 2
    for (int ks = 0; ks < KSTEPS; ++ks) {
        bf16x8 w[2], a[2];
        #pragma unroll
        for (int nr = 0; nr < 2; ++nr)
            w[nr] = *(const bf16x8*)(wnb + ((ks*2 + nr) << 9));
        #pragma unroll
        for (int mr = 0; mr < 2; ++mr) {
            int row = mr*32 + l31;
            a[mr] = *(const bf16x8*)(sm + ((((row << 10) + ks*32 + hi*16)) ^ ((row & 15) << 4)));
        }
        #pragma unroll
        for (int mr = 0; mr < 2; ++mr)
            #pragma unroll
            for (int nr = 0; nr < 2; ++nr)
                acc[mr][nr] = __builtin_amdgcn_mfma_f32_32x32x16_bf16(w[nr], a[mr], acc[mr][nr], 0, 0, 0);
    }
    if (TAIL) {   // K-tail of 32 (= 2 k-steps) from the h0 block (64B rows, (row&7)<<4 swizzle)
        #pragma unroll
        for (int kt = 0; kt < 2; ++kt) {
            bf16x8 w[2], a[2];
            #pragma unroll
            for (int nr = 0; nr < 2; ++nr)
                w[nr] = *(const bf16x8*)(wnb + (((KSTEPS + kt)*2 + nr) << 9));
            #pragma unroll
            for (int mr = 0; mr < 2; ++mr) {
                int row = mr*32 + l31;
                a[mr] = *(const bf16x8*)(sm + H0_OFF + ((((row << 6) + kt*32 + hi*16)) ^ ((row & 7) << 4)));
            }
            #pragma unroll
            for (int mr = 0; mr < 2; ++mr)
                #pragma unroll
                for (int nr = 0; nr < 2; ++nr)
                    acc[mr][nr] = __builtin_amdgcn_mfma_f32_32x32x16_bf16(w[nr], a[mr], acc[mr][nr], 0, 0, 0);
        }
    }

    if (PREBAR) __syncthreads();    // all waves done reading act before overwrite

    // epilogue: lane's act row m = mr*32+l31; n = n0 + nr*32 + q*8 + hi*4 + {0..3}
    #pragma unroll
    for (int mr = 0; mr < 2; ++mr) {
        const int m    = mr*32 + l31;
        const int rowb = m << 10;
        const int sw   = (m & 15) << 4;
        #pragma unroll
        for (int nr = 0; nr < 2; ++nr) {
            #pragma unroll
            for (int q = 0; q < 4; ++q) {
                const int nb4 = n0 + nr*32 + q*8 + hi*4;
                const float4 bv = *(const float4*)(bias + nb4);
                float s0 = __sinf(acc[mr][nr][q*4+0] + bv.x);
                float s1 = __sinf(acc[mr][nr][q*4+1] + bv.y);
                float s2 = __sinf(acc[mr][nr][q*4+2] + bv.z);
                float s3 = __sinf(acc[mr][nr][q*4+3] + bv.w);
                uint2 pk;
                pk.x = (unsigned)f2bf(s0) | ((unsigned)f2bf(s1) << 16);
                pk.y = (unsigned)f2bf(s2) | ((unsigned)f2bf(s3) << 16);
                *(uint2*)(sm + ((rowb + nb4*2) ^ sw)) = pk;
            }
        }
    }
    __syncthreads();
}

__global__ __launch_bounds__(512) __attribute__((amdgpu_waves_per_eu(4))) void siren_fused(
    const float* __restrict__ coords, const float* __restrict__ table,
    const float* __restrict__ b1, const float* __restrict__ b2,
    const float* __restrict__ bs1, const float* __restrict__ bs2,
    const float* __restrict__ bo,
    const unsigned short* __restrict__ Wp,
    float* __restrict__ outp,
    ResArr res)
{
    extern __shared__ char sm[];
    const int tid = threadIdx.x;
    const int pbase = blockIdx.x * MBLK;

    // ---------------- hash encoding -> h0 block (64B rows, (p&7)<<4 swizzle) ----------------
    {
        int p  = tid & 63;
        int lg = tid >> 6;                 // 0..7; handles levels lg, lg+8
        float2 cc = ((const float2*)coords)[pbase + p];
        #pragma unroll
        for (int li = 0; li < 2; ++li) {
            int l = lg + 8 * li;
            if (l < 10) {
                float R  = (float)res.r[l];
                float fx = cc.x * R, fy = cc.y * R;
                float x0 = floorf(fx), y0 = floorf(fy);
                float wx = fx - x0,  wy = fy - y0;
                unsigned xi = (unsigned)x0, yi = (unsigned)y0;
                unsigned yp  = yi * 2654435761u;
                unsigned yp1 = (yi + 1u) * 2654435761u;
                unsigned h00 = (xi        ^ yp ) & 4095u;
                unsigned h10 = ((xi + 1u) ^ yp ) & 4095u;
                unsigned h01 = (xi        ^ yp1) & 4095u;
                unsigned h11 = ((xi + 1u) ^ yp1) & 4095u;
                const float2* tl = (const float2*)(table + l * 8192);
                float2 f00 = tl[h00], f10 = tl[h10], f01 = tl[h01], f11 = tl[h11];
                float a0 = f00.x + (f10.x - f00.x) * wx;
                float a1 = f01.x + (f11.x - f01.x) * wx;
                float g0 = a0 + (a1 - a0) * wy;
                float c0 = f00.y + (f10.y - f00.y) * wx;
                float c1 = f01.y + (f11.y - f01.y) * wx;
                float g1 = c0 + (c1 - c0) * wy;
                unsigned pk = (unsigned)f2bf(g0) | ((unsigned)f2bf(g1) << 16);
                *(unsigned*)(sm + H0_OFF + (((p << 6) + 4*l) ^ ((p & 7) << 4))) = pk;
            }
        }
        if (lg == 2) {   // coords -> cols 20,21 (byte 40)
            unsigned pk = (unsigned)f2bf(cc.x) | ((unsigned)f2bf(cc.y) << 16);
            *(unsigned*)(sm + H0_OFF + (((p << 6) + 40) ^ ((p & 7) << 4))) = pk;
        }
        if (lg == 3) {   // zero pad cols 22..31 (bytes 44..63)
            #pragma unroll
            for (int bb = 44; bb < 64; bb += 4)
                *(unsigned*)(sm + H0_OFF + (((p << 6) + bb) ^ ((p & 7) << 4))) = 0u;
        }
    }
    __syncthreads();

    const int wid  = tid >> 6;
    const int lane = tid & 63;

    mlp_layer<0,  true,  false>(sm, Wp + OFF_W1,  b1,  wid, lane);  // h0 -> act
    mlp_layer<32, false, true >(sm, Wp + OFF_W2,  b2,  wid, lane);  // act -> act
    mlp_layer<32, true,  true >(sm, Wp + OFF_WS1, bs1, wid, lane);  // [act|h0] -> act
    mlp_layer<32, false, true >(sm, Wp + OFF_WS2, bs2, wid, lane);  // act -> act

    // ---------------- output layer: 512 -> 2, sin, f32 out ----------------
    {
        int p = tid >> 3, g = tid & 7;
        const unsigned short* wo0 = Wp + OFF_WO + g * 64;
        const unsigned short* wo1 = wo0 + 512;
        int xm = (p & 15) << 4;
        float s0 = 0.f, s1 = 0.f;
        #pragma unroll
        for (int kk = 0; kk < 8; ++kk) {
            int off = ((p << 10) + g*128 + kk*16) ^ xm;
            bf16x8 av  = *(const bf16x8*)(sm + off);
            bf16x8 w0  = *(const bf16x8*)(wo0 + kk * 8);
            bf16x8 w1v = *(const bf16x8*)(wo1 + kk * 8);
            #pragma unroll
            for (int j = 0; j < 8; ++j) {
                float a = bf2f((unsigned short)av[j]);
                s0 += a * bf2f((unsigned short)w0[j]);
                s1 += a * bf2f((unsigned short)w1v[j]);
            }
        }
        #pragma unroll
        for (int m = 1; m < 8; m <<= 1) {
            s0 += __shfl_xor(s0, m, 64);
            s1 += __shfl_xor(s1, m, 64);
        }
        if (g == 0) {
            float2 o;
            o.x = __sinf(s0 + bo[0]);
            o.y = __sinf(s1 + bo[1]);
            ((float2*)outp)[pbase + p] = o;
        }
    }
}

extern "C" void kernel_launch(void* const* d_in, const int* in_sizes, int n_in,
                              void* d_out, int out_size, void* d_ws, size_t ws_size,
                              hipStream_t stream)
{
    const float* coords = (const float*)d_in[0];
    const float* table  = (const float*)d_in[1];
    const float* w1  = (const float*)d_in[2];
    const float* b1  = (const float*)d_in[3];
    const float* w2  = (const float*)d_in[4];
    const float* b2  = (const float*)d_in[5];
    const float* ws1 = (const float*)d_in[6];
    const float* bs1 = (const float*)d_in[7];
    const float* ws2 = (const float*)d_in[8];
    const float* bs2 = (const float*)d_in[9];
    const float* wo  = (const float*)d_in[10];
    const float* bo  = (const float*)d_in[11];

    unsigned short* Wp = (unsigned short*)d_ws;
    float* outp = (float*)d_out;

    // RES computed with the exact double-precision op sequence of the reference
    ResArr res;
    double bb = exp((log(320.0) - log(16.0)) / 9.0);
    for (int l = 0; l < 10; ++l) res.r[l] = (int)floor(16.0 * pow(bb, (double)l));

    (void)hipFuncSetAttribute((const void*)siren_fused,
                              hipFuncAttributeMaxDynamicSharedMemorySize, LDSB);

    int N = in_sizes[0] / 2;      // 262144

    pack_weights<<<(NPACK + 255) / 256, 256, 0, stream>>>(w1, w2, ws1, ws2, wo, Wp);
    siren_fused<<<N / MBLK, 512, LDSB, stream>>>(coords, table, b1, b2, bs1, bs2, bo,
                                                 Wp, outp, res);
}

// Round 12
// 405.337 us; speedup vs baseline: 1.1386x; 1.1386x over previous
//
#include <hip/hip_runtime.h>
#include <hip/hip_bf16.h>
#include <math.h>

#define MBLK    64
#define H0_OFF  65536                 // act: 64 rows x 1024B (512 bf16), XOR-swizzled (row&15)<<4
#define LDSB    (H0_OFF + 64*64)      // +h0: 64 rows x 64B -> 69632 (2 blocks/CU)
#define INV2PI  0.15915494309189535f

// packed bf16 weight offsets (ushort elements) inside d_ws — all weights PRE-SCALED by 1/2pi
// layout per layer: [nb(8)][chunk(KC)][nf(4)][lane(64)][j(8)]  (coalesced per-wave loads)
#define OFF_W1  0
#define OFF_W2  16384                    // 8*1*4*512
#define OFF_WS1 (16384+262144)           // 278528
#define OFF_WS2 (278528+278528)          // 557056
#define OFF_WO  (557056+262144)          // 819200 (wo row-major, 1024)
#define NPACK   (819200+1024)            // 820224

typedef __attribute__((ext_vector_type(8))) short bf16x8;
typedef __attribute__((ext_vector_type(4))) float f32x4;

struct ResArr { int r[10]; };

__device__ __forceinline__ unsigned short f2bf(float f) {
    unsigned u = __float_as_uint(f);
    u += 0x7FFFu + ((u >> 16) & 1u);       // RNE
    return (unsigned short)(u >> 16);
}
__device__ __forceinline__ float bf2f(unsigned short h) {
    return __uint_as_float(((unsigned)h) << 16);
}
__device__ __forceinline__ float hwsin(float x) {   // sin(2*pi*x) via v_sin_f32
    float r;
    asm("v_sin_f32 %0, %1" : "=v"(r) : "v"(x));
    return r;
}
// round two f32 to bf16 (RNE) and pack into one u32: low=bf16(a), high=bf16(b)
__device__ __forceinline__ unsigned pack_bf16_rne(float a, float b) {
    unsigned ua = __float_as_uint(a);
    unsigned ub = __float_as_uint(b);
    ua += 0x7FFFu + ((ua >> 16) & 1u);
    ub += 0x7FFFu + ((ub >> 16) & 1u);
    return __builtin_amdgcn_perm(ub, ua, 0x07060302u);  // {ub.hi16, ua.hi16}
}

__global__ void pack_weights(const float* __restrict__ w1, const float* __restrict__ w2,
                             const float* __restrict__ ws1, const float* __restrict__ ws2,
                             const float* __restrict__ wo, unsigned short* __restrict__ out)
{
    int i = blockIdx.x * 256 + threadIdx.x;
    if (i >= NPACK) return;
    float v;
    if (i < OFF_WO) {
        int il, KC, K_src, K_valid;
        const float* src;
        if (i < OFF_W2)       { il = i;           KC = 1;  K_src = 22;  K_valid = 22;  src = w1;  }
        else if (i < OFF_WS1) { il = i - OFF_W2;  KC = 16; K_src = 512; K_valid = 512; src = w2;  }
        else if (i < OFF_WS2) { il = i - OFF_WS1; KC = 17; K_src = 534; K_valid = 534; src = ws1; }
        else                  { il = i - OFF_WS2; KC = 16; K_src = 512; K_valid = 512; src = ws2; }
        int blk  = il >> 9, idx = il & 511;
        int lane = idx >> 3, j = idx & 7;
        int nf   = blk & 3;
        int rest = blk >> 2;
        int c    = rest % KC;
        int nb   = rest / KC;
        int n = nb * 64 + nf * 16 + (lane & 15);
        int k = c * 32 + (lane >> 4) * 8 + j;
        v = (k < K_valid) ? src[n * K_src + k] : 0.f;
    } else {
        v = wo[i - OFF_WO];
    }
    out[i] = f2bf(v * INV2PI);
}

// One MLP layer, in-place on the 64x512 act buffer. 8 waves; wave owns 64 rows x 64 cols.
// SWAPPED operands: acc = mfma(W_frag, act_frag) => D: row(lk*4+j)=n-local, col(lane&15)=act row
template<int KSTEPS, bool TAIL, bool PREBAR>
__device__ __forceinline__ void mlp_layer(char* sm, const unsigned short* __restrict__ Wl,
                                          const float* __restrict__ bias,
                                          int wid, int lane)
{
    constexpr int NC = KSTEPS + (TAIL ? 1 : 0);
    const int n0 = wid * 64;
    const int lm = lane & 15;
    const int lk = lane >> 4;               // 0..3
    const int xm = lm << 4;                 // act swizzle: (row&15)<<4, row=mf*16+lm -> lm<<4

    const unsigned short* wnb = Wl + (unsigned)(wid * NC) * 2048 + (lane << 3);

    f32x4 acc[4][4];
    #pragma unroll
    for (int i = 0; i < 4; ++i)
        #pragma unroll
        for (int j = 0; j < 4; ++j) { f32x4 z = {0.f,0.f,0.f,0.f}; acc[i][j] = z; }

    #pragma unroll 1
    for (int ks = 0; ks < KSTEPS; ++ks) {
        bf16x8 w[4], a[4];
        #pragma unroll
        for (int nf = 0; nf < 4; ++nf)
            w[nf] = *(const bf16x8*)(wnb + ((ks*4 + nf) << 9));
        #pragma unroll
        for (int mf = 0; mf < 4; ++mf)
            a[mf] = *(const bf16x8*)(sm + ((((mf*16 + lm) << 10) + ks*64 + lk*16) ^ xm));
        #pragma unroll
        for (int mf = 0; mf < 4; ++mf)
            #pragma unroll
            for (int nf = 0; nf < 4; ++nf)
                acc[mf][nf] = __builtin_amdgcn_mfma_f32_16x16x32_bf16(w[nf], a[mf], acc[mf][nf], 0, 0, 0);
    }
    if (TAIL) {   // K-tail of 32 from the h0 block (64B rows, (row&7)<<4 swizzle)
        bf16x8 w[4], a[4];
        #pragma unroll
        for (int nf = 0; nf < 4; ++nf)
            w[nf] = *(const bf16x8*)(wnb + ((KSTEPS*4 + nf) << 9));
        #pragma unroll
        for (int mf = 0; mf < 4; ++mf)
            a[mf] = *(const bf16x8*)(sm + H0_OFF + ((((mf*16 + lm) << 6) + lk*16) ^ ((lm & 7) << 4)));
        #pragma unroll
        for (int mf = 0; mf < 4; ++mf)
            #pragma unroll
            for (int nf = 0; nf < 4; ++nf)
                acc[mf][nf] = __builtin_amdgcn_mfma_f32_16x16x32_bf16(w[nf], a[mf], acc[mf][nf], 0, 0, 0);
    }

    if (PREBAR) __syncthreads();    // all waves done reading act before overwrite

    // epilogue: s = v_sin(acc + b/2pi)  (weights pre-scaled by 1/2pi -> sin(Wx+b))
    #pragma unroll
    for (int nf = 0; nf < 4; ++nf) {
        const float4 bv = *(const float4*)(bias + n0 + nf*16 + lk*4);
        const int colb = (n0 + nf*16 + lk*4) * 2;
        #pragma unroll
        for (int mf = 0; mf < 4; ++mf) {
            float s0 = hwsin(acc[mf][nf][0] + bv.x * INV2PI);
            float s1 = hwsin(acc[mf][nf][1] + bv.y * INV2PI);
            float s2 = hwsin(acc[mf][nf][2] + bv.z * INV2PI);
            float s3 = hwsin(acc[mf][nf][3] + bv.w * INV2PI);
            uint2 pk;
            pk.x = pack_bf16_rne(s0, s1);
            pk.y = pack_bf16_rne(s2, s3);
            int row = mf*16 + lm;
            *(uint2*)(sm + (((row << 10) + colb) ^ xm)) = pk;
        }
    }
    __syncthreads();
}

__global__ __launch_bounds__(512) __attribute__((amdgpu_waves_per_eu(4))) void siren_fused(
    const float* __restrict__ coords, const float* __restrict__ table,
    const float* __restrict__ b1, const float* __restrict__ b2,
    const float* __restrict__ bs1, const float* __restrict__ bs2,
    const float* __restrict__ bo,
    const unsigned short* __restrict__ Wp,
    float* __restrict__ outp,
    ResArr res)
{
    extern __shared__ char sm[];
    const int tid = threadIdx.x;
    const int pbase = blockIdx.x * MBLK;

    // ---------------- hash encoding -> h0 block (64B rows, (p&7)<<4 swizzle) ----------------
    {
        int p  = tid & 63;
        int lg = tid >> 6;                 // 0..7; handles levels lg, lg+8
        float2 cc = ((const float2*)coords)[pbase + p];
        #pragma unroll
        for (int li = 0; li < 2; ++li) {
            int l = lg + 8 * li;
            if (l < 10) {
                float R  = (float)res.r[l];
                float fx = cc.x * R, fy = cc.y * R;
                float x0 = floorf(fx), y0 = floorf(fy);
                float wx = fx - x0,  wy = fy - y0;
                unsigned xi = (unsigned)x0, yi = (unsigned)y0;
                unsigned yp  = yi * 2654435761u;
                unsigned yp1 = (yi + 1u) * 2654435761u;
                unsigned h00 = (xi        ^ yp ) & 4095u;
                unsigned h10 = ((xi + 1u) ^ yp ) & 4095u;
                unsigned h01 = (xi        ^ yp1) & 4095u;
                unsigned h11 = ((xi + 1u) ^ yp1) & 4095u;
                const float2* tl = (const float2*)(table + l * 8192);
                float2 f00 = tl[h00], f10 = tl[h10], f01 = tl[h01], f11 = tl[h11];
                float a0 = f00.x + (f10.x - f00.x) * wx;
                float a1 = f01.x + (f11.x - f01.x) * wx;
                float g0 = a0 + (a1 - a0) * wy;
                float c0 = f00.y + (f10.y - f00.y) * wx;
                float c1 = f01.y + (f11.y - f01.y) * wx;
                float g1 = c0 + (c1 - c0) * wy;
                unsigned pk = (unsigned)f2bf(g0) | ((unsigned)f2bf(g1) << 16);
                *(unsigned*)(sm + H0_OFF + (((p << 6) + 4*l) ^ ((p & 7) << 4))) = pk;
            }
        }
        if (lg == 2) {   // coords -> cols 20,21 (byte 40)
            unsigned pk = (unsigned)f2bf(cc.x) | ((unsigned)f2bf(cc.y) << 16);
            *(unsigned*)(sm + H0_OFF + (((p << 6) + 40) ^ ((p & 7) << 4))) = pk;
        }
        if (lg == 3) {   // zero pad cols 22..31 (bytes 44..63)
            #pragma unroll
            for (int bb = 44; bb < 64; bb += 4)
                *(unsigned*)(sm + H0_OFF + (((p << 6) + bb) ^ ((p & 7) << 4))) = 0u;
        }
    }
    __syncthreads();

    const int wid  = tid >> 6;
    const int lane = tid & 63;

    mlp_layer<0,  true,  false>(sm, Wp + OFF_W1,  b1,  wid, lane);  // h0 -> act
    mlp_layer<16, false, true >(sm, Wp + OFF_W2,  b2,  wid, lane);  // act -> act
    mlp_layer<16, true,  true >(sm, Wp + OFF_WS1, bs1, wid, lane);  // [act|h0] -> act
    mlp_layer<16, false, true >(sm, Wp + OFF_WS2, bs2, wid, lane);  // act -> act

    // ---------------- output layer: 512 -> 2, sin (wo pre-scaled), f32 out ----------------
    {
        int p = tid >> 3, g = tid & 7;
        const unsigned short* wo0 = Wp + OFF_WO + g * 64;
        const unsigned short* wo1 = wo0 + 512;
        int xm = (p & 15) << 4;
        float s0 = 0.f, s1 = 0.f;
        #pragma unroll
        for (int kk = 0; kk < 8; ++kk) {
            int off = ((p << 10) + g*128 + kk*16) ^ xm;
            bf16x8 av  = *(const bf16x8*)(sm + off);
            bf16x8 w0  = *(const bf16x8*)(wo0 + kk * 8);
            bf16x8 w1v = *(const bf16x8*)(wo1 + kk * 8);
            #pragma unroll
            for (int j = 0; j < 8; ++j) {
                float a = bf2f((unsigned short)av[j]);
                s0 += a * bf2f((unsigned short)w0[j]);
                s1 += a * bf2f((unsigned short)w1v[j]);
            }
        }
        #pragma unroll
        for (int m = 1; m < 8; m <<= 1) {
            s0 += __shfl_xor(s0, m, 64);
            s1 += __shfl_xor(s1, m, 64);
        }
        if (g == 0) {
            float2 o;
            o.x = hwsin(s0 + bo[0] * INV2PI);
            o.y = hwsin(s1 + bo[1] * INV2PI);
            ((float2*)outp)[pbase + p] = o;
        }
    }
}

extern "C" void kernel_launch(void* const* d_in, const int* in_sizes, int n_in,
                              void* d_out, int out_size, void* d_ws, size_t ws_size,
                              hipStream_t stream)
{
    const float* coords = (const float*)d_in[0];
    const float* table  = (const float*)d_in[1];
    const float* w1  = (const float*)d_in[2];
    const float* b1  = (const float*)d_in[3];
    const float* w2  = (const float*)d_in[4];
    const float* b2  = (const float*)d_in[5];
    const float* ws1 = (const float*)d_in[6];
    const float* bs1 = (const float*)d_in[7];
    const float* ws2 = (const float*)d_in[8];
    const float* bs2 = (const float*)d_in[9];
    const float* wo  = (const float*)d_in[10];
    const float* bo  = (const float*)d_in[11];

    unsigned short* Wp = (unsigned short*)d_ws;
    float* outp = (float*)d_out;

    // RES computed with the exact double-precision op sequence of the reference
    ResArr res;
    double bb = exp((log(320.0) - log(16.0)) / 9.0);
    for (int l = 0; l < 10; ++l) res.r[l] = (int)floor(16.0 * pow(bb, (double)l));

    (void)hipFuncSetAttribute((const void*)siren_fused,
                              hipFuncAttributeMaxDynamicSharedMemorySize, LDSB);

    int N = in_sizes[0] / 2;      // 262144

    pack_weights<<<(NPACK + 255) / 256, 256, 0, stream>>>(w1, w2, ws1, ws2, wo, Wp);
    siren_fused<<<N / MBLK, 512, LDSB, stream>>>(coords, table, b1, b2, bs1, bs2, bo,
                                                 Wp, outp, res);
}

// Round 13
// 372.997 us; speedup vs baseline: 1.2374x; 1.0867x over previous
//
#include <hip/hip_runtime.h>
#include <hip/hip_bf16.h>
#include <math.h>

#define MBLK    64
#define CHUNK   4096                  // one k-chunk: 64 rows x 32 bf16 = 4KB
#define H0_OFF  65536                 // act: 16 chunks; h0: 1 chunk at 65536
#define LDSB    (H0_OFF + CHUNK)      // 69632 (2 blocks/CU)
#define INV2PI  0.15915494309189535f

// packed bf16 weights (ushort elems) in d_ws — all PRE-SCALED by 1/2pi
// hidden layers: [nb(8)][ks(KC)][nf(4)][lane(64)][j(8)]
// output wo:     [half(2)][ks(8)][lane(64)][j(8)]  (n=lane&15, only n<2 nonzero)
#define OFF_W1  0
#define OFF_W2  16384
#define OFF_WS1 (16384+262144)           // 278528
#define OFF_WS2 (278528+278528)          // 557056
#define OFF_WO  (557056+262144)          // 819200
#define NPACK   (819200+8192)            // 827392

typedef __attribute__((ext_vector_type(8))) short bf16x8;
typedef __attribute__((ext_vector_type(4))) float f32x4;

struct ResArr { int r[10]; };

__device__ __forceinline__ unsigned short f2bf(float f) {
    unsigned u = __float_as_uint(f);
    u += 0x7FFFu + ((u >> 16) & 1u);       // RNE
    return (unsigned short)(u >> 16);
}
__device__ __forceinline__ float bf2f(unsigned short h) {
    return __uint_as_float(((unsigned)h) << 16);
}
__device__ __forceinline__ float hwsin(float x) {   // sin(2*pi*x)
    float r;
    asm("v_sin_f32 %0, %1" : "=v"(r) : "v"(x));
    return r;
}
__device__ __forceinline__ unsigned pack_bf16_rne(float a, float b) {
    unsigned ua = __float_as_uint(a);
    unsigned ub = __float_as_uint(b);
    ua += 0x7FFFu + ((ua >> 16) & 1u);
    ub += 0x7FFFu + ((ub >> 16) & 1u);
    return __builtin_amdgcn_perm(ub, ua, 0x07060302u);
}

__global__ void pack_weights(const float* __restrict__ w1, const float* __restrict__ w2,
                             const float* __restrict__ ws1, const float* __restrict__ ws2,
                             const float* __restrict__ wo, unsigned short* __restrict__ out)
{
    int i = blockIdx.x * 256 + threadIdx.x;
    if (i >= NPACK) return;
    float v;
    if (i < OFF_WO) {
        int il, KC, K_src, K_valid;
        const float* src;
        if (i < OFF_W2)       { il = i;           KC = 1;  K_src = 22;  K_valid = 22;  src = w1;  }
        else if (i < OFF_WS1) { il = i - OFF_W2;  KC = 16; K_src = 512; K_valid = 512; src = w2;  }
        else if (i < OFF_WS2) { il = i - OFF_WS1; KC = 17; K_src = 534; K_valid = 534; src = ws1; }
        else                  { il = i - OFF_WS2; KC = 16; K_src = 512; K_valid = 512; src = ws2; }
        int blk  = il >> 9, idx = il & 511;
        int lane = idx >> 3, j = idx & 7;
        int nf   = blk & 3;
        int rest = blk >> 2;
        int c    = rest % KC;
        int nb   = rest / KC;
        int n = nb * 64 + nf * 16 + (lane & 15);
        int k = c * 32 + (lane >> 4) * 8 + j;
        v = (k < K_valid) ? src[n * K_src + k] : 0.f;
    } else {
        int j = i - OFF_WO;
        int h = j >> 12, ks = (j >> 9) & 7, lane = (j >> 3) & 63, jj = j & 7;
        int n = lane & 15;
        int k = h * 256 + ks * 32 + (lane >> 4) * 8 + jj;
        v = (n < 2) ? wo[n * 512 + k] : 0.f;
    }
    out[i] = f2bf(v * INV2PI);
}

// One MLP layer, in-place on the chunked act buffer. 8 waves; wave owns 64 rows x 64 cols.
// acc = mfma(W_frag, act_frag): D col(lane&15)=act row, row(lk*4+j)=n-local
template<int KSTEPS, bool TAIL, bool PREBAR>
__device__ __forceinline__ void mlp_layer(char* sm, const unsigned short* __restrict__ Wl,
                                          const float* __restrict__ bias,
                                          int wid, int lane)
{
    constexpr int NC = KSTEPS + (TAIL ? 1 : 0);
    const int n0 = wid * 64;
    const int lm = lane & 15;
    const int lk = lane >> 4;
    const int sw = (lm & 7) << 4;
    const int rbase = (lm*64 + lk*16) ^ sw;       // chunk-0 read base; +mf*1024 imm; +c*4096

    const unsigned short* up = Wl + (unsigned)(__builtin_amdgcn_readfirstlane(wid) * NC) * 2048;
    const int lo8 = lane << 3;

    f32x4 acc[4][4];
    #pragma unroll
    for (int i = 0; i < 4; ++i)
        #pragma unroll
        for (int j = 0; j < 4; ++j) { f32x4 z = {0.f,0.f,0.f,0.f}; acc[i][j] = z; }

    const char* ab = sm + rbase;
    #pragma unroll 1
    for (int ks = 0; ks < KSTEPS; ++ks) {
        bf16x8 w[4], a[4];
        #pragma unroll
        for (int nf = 0; nf < 4; ++nf)
            w[nf] = *(const bf16x8*)(up + nf*512 + lo8);
        #pragma unroll
        for (int mf = 0; mf < 4; ++mf)
            a[mf] = *(const bf16x8*)(ab + mf*1024);
        #pragma unroll
        for (int mf = 0; mf < 4; ++mf)
            #pragma unroll
            for (int nf = 0; nf < 4; ++nf)
                acc[mf][nf] = __builtin_amdgcn_mfma_f32_16x16x32_bf16(w[nf], a[mf], acc[mf][nf], 0, 0, 0);
        up += 2048;
        ab += CHUNK;
    }
    if (TAIL) {   // K-tail 32 from h0 chunk
        bf16x8 w[4], a[4];
        #pragma unroll
        for (int nf = 0; nf < 4; ++nf)
            w[nf] = *(const bf16x8*)(up + nf*512 + lo8);
        #pragma unroll
        for (int mf = 0; mf < 4; ++mf)
            a[mf] = *(const bf16x8*)(sm + H0_OFF + rbase + mf*1024);
        #pragma unroll
        for (int mf = 0; mf < 4; ++mf)
            #pragma unroll
            for (int nf = 0; nf < 4; ++nf)
                acc[mf][nf] = __builtin_amdgcn_mfma_f32_16x16x32_bf16(w[nf], a[mf], acc[mf][nf], 0, 0, 0);
    }

    if (PREBAR) __syncthreads();

    // epilogue: addr = (row64 ^ (sw&64)) + ((cbw ^ (sw&48)) + chunkE*4096)
    int R[4], C[4];
    #pragma unroll
    for (int mf = 0; mf < 4; ++mf)
        R[mf] = ((mf*16 + lm) * 64) ^ (sw & 64);
    #pragma unroll
    for (int nf = 0; nf < 4; ++nf)
        C[nf] = (((nf & 1)*32 + lk*8) ^ (sw & 48)) + (wid*2 + (nf >> 1)) * CHUNK;

    #pragma unroll
    for (int nf = 0; nf < 4; ++nf) {
        const float4 bv = *(const float4*)(bias + n0 + nf*16 + lk*4);
        #pragma unroll
        for (int mf = 0; mf < 4; ++mf) {
            float s0 = hwsin(fmaf(bv.x, INV2PI, acc[mf][nf][0]));
            float s1 = hwsin(fmaf(bv.y, INV2PI, acc[mf][nf][1]));
            float s2 = hwsin(fmaf(bv.z, INV2PI, acc[mf][nf][2]));
            float s3 = hwsin(fmaf(bv.w, INV2PI, acc[mf][nf][3]));
            uint2 pk;
            pk.x = pack_bf16_rne(s0, s1);
            pk.y = pack_bf16_rne(s2, s3);
            *(uint2*)(sm + (R[mf] + C[nf])) = pk;
        }
    }
    __syncthreads();
}

__global__ __launch_bounds__(512) __attribute__((amdgpu_waves_per_eu(4))) void siren_fused(
    const float* __restrict__ coords, const float* __restrict__ table,
    const float* __restrict__ b1, const float* __restrict__ b2,
    const float* __restrict__ bs1, const float* __restrict__ bs2,
    const float* __restrict__ bo,
    const unsigned short* __restrict__ Wp,
    float* __restrict__ outp,
    ResArr res)
{
    extern __shared__ char sm[];
    const int tid = threadIdx.x;
    const int pbase = blockIdx.x * MBLK;

    // ---------------- hash encoding -> h0 chunk (64B rows, (p&7)<<4 swizzle) ----------------
    {
        int p  = tid & 63;
        int lg = tid >> 6;
        float2 cc = ((const float2*)coords)[pbase + p];
        #pragma unroll
        for (int li = 0; li < 2; ++li) {
            int l = lg + 8 * li;
            if (l < 10) {
                float R  = (float)res.r[l];
                float fx = cc.x * R, fy = cc.y * R;
                float x0 = floorf(fx), y0 = floorf(fy);
                float wx = fx - x0,  wy = fy - y0;
                unsigned xi = (unsigned)x0, yi = (unsigned)y0;
                unsigned yp  = yi * 2654435761u;
                unsigned yp1 = (yi + 1u) * 2654435761u;
                unsigned h00 = (xi        ^ yp ) & 4095u;
                unsigned h10 = ((xi + 1u) ^ yp ) & 4095u;
                unsigned h01 = (xi        ^ yp1) & 4095u;
                unsigned h11 = ((xi + 1u) ^ yp1) & 4095u;
                const float2* tl = (const float2*)(table + l * 8192);
                float2 f00 = tl[h00], f10 = tl[h10], f01 = tl[h01], f11 = tl[h11];
                float a0 = f00.x + (f10.x - f00.x) * wx;
                float a1 = f01.x + (f11.x - f01.x) * wx;
                float g0 = a0 + (a1 - a0) * wy;
                float c0 = f00.y + (f10.y - f00.y) * wx;
                float c1 = f01.y + (f11.y - f01.y) * wx;
                float g1 = c0 + (c1 - c0) * wy;
                unsigned pk = (unsigned)f2bf(g0) | ((unsigned)f2bf(g1) << 16);
                *(unsigned*)(sm + H0_OFF + (((p << 6) + 4*l) ^ ((p & 7) << 4))) = pk;
            }
        }
        if (lg == 2) {
            unsigned pk = (unsigned)f2bf(cc.x) | ((unsigned)f2bf(cc.y) << 16);
            *(unsigned*)(sm + H0_OFF + (((p << 6) + 40) ^ ((p & 7) << 4))) = pk;
        }
        if (lg == 3) {
            #pragma unroll
            for (int bb = 44; bb < 64; bb += 4)
                *(unsigned*)(sm + H0_OFF + (((p << 6) + bb) ^ ((p & 7) << 4))) = 0u;
        }
    }
    __syncthreads();

    const int wid  = tid >> 6;
    const int lane = tid & 63;

    mlp_layer<0,  true,  false>(sm, Wp + OFF_W1,  b1,  wid, lane);  // h0 -> act
    mlp_layer<16, false, true >(sm, Wp + OFF_W2,  b2,  wid, lane);  // act -> act
    mlp_layer<16, true,  true >(sm, Wp + OFF_WS1, bs1, wid, lane);  // [act|h0] -> act
    mlp_layer<16, false, true >(sm, Wp + OFF_WS2, bs2, wid, lane);  // act -> act

    // ---------------- output layer: 512 -> 2 via MFMA split-K ----------------
    {
        const int lm = lane & 15;
        const int lk = lane >> 4;
        const int r0 = (wid & 3) * 16;          // row tile
        const int h  = __builtin_amdgcn_readfirstlane(wid) >> 2;  // K half
        const int rbase = (((r0 + lm)*64 + lk*16) ^ ((lm & 7) << 4)) + h*8*CHUNK;
        const unsigned short* uo = Wp + OFF_WO + h*4096;
        const int lo8 = lane << 3;

        f32x4 acc = {0.f, 0.f, 0.f, 0.f};
        #pragma unroll
        for (int ks = 0; ks < 8; ++ks) {
            bf16x8 w = *(const bf16x8*)(uo + ks*512 + lo8);
            bf16x8 a = *(const bf16x8*)(sm + rbase + ks*CHUNK);
            acc = __builtin_amdgcn_mfma_f32_16x16x32_bf16(w, a, acc, 0, 0, 0);
        }
        __syncthreads();   // act reads done; h0 area reusable for partials
        if (lk == 0) {
            float2 part; part.x = acc[0]; part.y = acc[1];
            *(float2*)(sm + H0_OFF + (h*64 + r0 + lm)*8) = part;
        }
    }
    __syncthreads();
    if (tid < 64) {
        float2 p0 = *(const float2*)(sm + H0_OFF + tid*8);
        float2 p1 = *(const float2*)(sm + H0_OFF + 512 + tid*8);
        float2 o;
        o.x = hwsin(fmaf(bo[0], INV2PI, p0.x + p1.x));
        o.y = hwsin(fmaf(bo[1], INV2PI, p0.y + p1.y));
        ((float2*)outp)[pbase + tid] = o;
    }
}

extern "C" void kernel_launch(void* const* d_in, const int* in_sizes, int n_in,
                              void* d_out, int out_size, void* d_ws, size_t ws_size,
                              hipStream_t stream)
{
    const float* coords = (const float*)d_in[0];
    const float* table  = (const float*)d_in[1];
    const float* w1  = (const float*)d_in[2];
    const float* b1  = (const float*)d_in[3];
    const float* w2  = (const float*)d_in[4];
    const float* b2  = (const float*)d_in[5];
    const float* ws1 = (const float*)d_in[6];
    const float* bs1 = (const float*)d_in[7];
    const float* ws2 = (const float*)d_in[8];
    const float* bs2 = (const float*)d_in[9];
    const float* wo  = (const float*)d_in[10];
    const float* bo  = (const float*)d_in[11];

    unsigned short* Wp = (unsigned short*)d_ws;
    float* outp = (float*)d_out;

    ResArr res;
    double bb = exp((log(320.0) - log(16.0)) / 9.0);
    for (int l = 0; l < 10; ++l) res.r[l] = (int)floor(16.0 * pow(bb, (double)l));

    (void)hipFuncSetAttribute((const void*)siren_fused,
                              hipFuncAttributeMaxDynamicSharedMemorySize, LDSB);

    int N = in_sizes[0] / 2;      // 262144

    pack_weights<<<(NPACK + 255) / 256, 256, 0, stream>>>(w1, w2, ws1, ws2, wo, Wp);
    siren_fused<<<N / MBLK, 512, LDSB, stream>>>(coords, table, b1, b2, bs1, bs2, bo,
                                                 Wp, outp, res);
}